// Round 5
// baseline (1324.747 us; speedup 1.0000x reference)
//
#include <hip/hip_runtime.h>
#include <math.h>

typedef unsigned short u16;
typedef unsigned int   u32;

#define NROWS 32768   // BS*NAG
#define NAG 8
#define HID 256
#define INP 128
#define G3  768
#define NACT 16
#define MESS 64
#define TRAJD 80
#define CAT 264        // HID+NAG
#define QIJK 320       // HID+MESS
#define QD 64
#define HOFF 524288    // element offset of h inside d_out (q is 32768*16)

// ---- ws layout in FLOAT offsets ----
#define WS_TRAJ  0          // bf16 u16[32768*80] = 1,310,720 floats
#define WS_QBASE 1310720    // fp32 [32768][16] = q_local + 0.5*(qij_b + h@qij_h)
#define WS_WTFC1 1835008    // [128][256]
#define WS_WTIH  1867776    // [256][768]
#define WS_WTHH  2064384    // [256][768]
#define WS_WTTR  2260992    // [264][256]
#define WS_DECW  2328576    // [16][256]
#define WS_QIJW  2332672    // [16][320]
#define WS_QW    2337792    // [64][80] x3 (q,k,v contiguous)
#define WS_CB    2353152    // packed biases, 2272 floats
#define WS_FLAG  2355424    // int: 1 = inputs fp32, 0 = bf16
// total ~9.42 MB

#define OB_FC1B 0
#define OB_BIH  256
#define OB_BHH  1024
#define OB_DECB 1792
#define OB_TRB  1808
#define OB_QIJB 2064
#define OB_QB   2080   // QB,KB,VB stride 64

__device__ __forceinline__ float bf2f(u16 v){ return __uint_as_float(((u32)v)<<16); }
__device__ __forceinline__ u16 f2bf(float f){
    u32 u = __float_as_uint(f);
    return (u16)((u + 0x7fffu + ((u>>16)&1u))>>16);   // RNE
}
__device__ __forceinline__ float sig_(float x){ return 1.0f/(1.0f+expf(-x)); }
__device__ __forceinline__ float ldin(const void* p, size_t i, int f32){
    return f32 ? ((const float*)p)[i] : bf2f(((const u16*)p)[i]);
}
__device__ __forceinline__ void stout2(void* out, size_t i, float v0, float v1, int f32){
    if (f32){ ((float*)out)[i]=v0; ((float*)out)[i+1]=v1; }
    else    { *(u32*)((u16*)out + i) = (u32)f2bf(v0) | ((u32)f2bf(v1)<<16); }
}
__device__ __forceinline__ void stout1(void* out, size_t i, float v, int f32){
    if (f32) ((float*)out)[i]=v; else ((u16*)out)[i]=f2bf(v);
}

// ---------------- k_det: sniff input dtype ----------------
__global__ void k_det(const void* __restrict__ inp, int* __restrict__ flag){
    __shared__ int cnt;
    if (threadIdx.x==0) cnt=0;
    __syncthreads();
    int big=0;
    for (int i=threadIdx.x;i<128;i+=64){
        u32 w = ((const u32*)inp)[i];
        float g = bf2f((u16)w);
        if (!(fabsf(g) <= 1e4f)) big++;
    }
    if (big) atomicAdd(&cnt, big);
    __syncthreads();
    if (threadIdx.x==0) *flag = (cnt>=4) ? 1 : 0;
}

// ---------------- k0: canonicalize all weights/biases to fp32 in ws ----------------
__global__ __launch_bounds__(256) void k0_prep(
    const void* fc1_w, const void* w_ih, const void* w_hh, const void* trans_w,
    const void* dec_w, const void* qij_w, const void* q_w, const void* k_w, const void* v_w,
    const void* fc1_b, const void* b_ih, const void* b_hh, const void* dec_b,
    const void* trans_b, const void* qij_b, const void* q_b, const void* k_b, const void* v_b,
    float* __restrict__ ws, const int* __restrict__ flagp)
{
    const int f32 = *flagp;
    int i = blockIdx.x*256 + threadIdx.x;
    if (i < 32768){ int c=i>>7, k=i&127; ws[WS_WTFC1 + k*HID + c] = ldin(fc1_w,i,f32); }
    if (i < 196608){ int r=i>>8, k=i&255;
        ws[WS_WTIH + k*G3 + r] = ldin(w_ih,i,f32);
        ws[WS_WTHH + k*G3 + r] = ldin(w_hh,i,f32); }
    if (i < 67584){ int c=i/CAT, k=i%CAT; ws[WS_WTTR + k*HID + c] = ldin(trans_w,i,f32); }
    if (i < 4096) ws[WS_DECW+i] = ldin(dec_w,i,f32);
    if (i < 5120){
        ws[WS_QIJW+i]=ldin(qij_w,i,f32);
        ws[WS_QW+i]        =ldin(q_w,i,f32);
        ws[WS_QW+5120+i]   =ldin(k_w,i,f32);
        ws[WS_QW+10240+i]  =ldin(v_w,i,f32); }
    if (i < 2272){
        float v;
        if      (i<256)  v=ldin(fc1_b,i,f32);
        else if (i<1024) v=ldin(b_ih,i-256,f32);
        else if (i<1792) v=ldin(b_hh,i-1024,f32);
        else if (i<1808) v=ldin(dec_b,i-1792,f32);
        else if (i<2064) v=ldin(trans_b,i-1808,f32);
        else if (i<2080) v=ldin(qij_b,i-2064,f32);
        else             v=ldin(q_b,i-2080,f32);
        if (i>=2144 && i<2208) v=ldin(k_b,i-2144,f32);
        if (i>=2208)           v=ldin(v_b,i-2208,f32);
        ws[WS_CB+i]=v;
    }
}

// ---------------- k12: fc1 + fused GRU + 5-step rollout, hc in LDS ----------------
__global__ __launch_bounds__(256) void k12_gru_rollout(
    const void* __restrict__ inp, const void* __restrict__ oldh,
    float* __restrict__ ws, void* __restrict__ dout, const int* __restrict__ flagp)
{
    __shared__ __align__(16) float pool[10240];
    float* s_in  = pool;
    float* s_x   = pool + 2048;
    float* s_oh  = pool + 6144;
    float* s_hc  = pool;
    float* s_q   = pool + 4224;
    float* s_ac  = pool + 4480;

    const int f32 = *flagp;
    const float* cb    = ws + WS_CB;
    const float* wtfc1 = ws + WS_WTFC1;
    const float* wtih  = ws + WS_WTIH;
    const float* wthh  = ws + WS_WTHH;
    const float* wttr  = ws + WS_WTTR;
    const float* decw  = ws + WS_DECW;
    const float* qijw  = ws + WS_QIJW;
    u16*   trajb = (u16*)(ws + WS_TRAJ);
    float* qbase = ws + WS_QBASE;

    const int t = threadIdx.x;
    const int row0 = blockIdx.x * 16;   // 2 batches per block
    const int rb = (t>>7)*8;            // row group 0 or 8
    const int c0 = (t&127)*2;           // even column pair

    for (int i=t;i<16*INP;i+=256){ int r=i>>7,k=i&127; s_in[r*INP+k]=ldin(inp,(size_t)(row0+r)*INP+k,f32); }
    for (int i=t;i<16*HID;i+=256){ int r=i>>8,k=i&255; s_oh[r*HID+k]=ldin(oldh,(size_t)(row0+r)*HID+k,f32); }
    __syncthreads();

    // ---- fc1 + relu -> s_x ----
    {
        float ax0[8], ax1[8];
        #pragma unroll
        for (int i=0;i<8;i++){ ax0[i]=0.f; ax1[i]=0.f; }
        for (int k4=0;k4<INP/4;k4++){
            float2 w0=*(const float2*)(wtfc1+(size_t)(4*k4+0)*HID+c0);
            float2 w1=*(const float2*)(wtfc1+(size_t)(4*k4+1)*HID+c0);
            float2 w2=*(const float2*)(wtfc1+(size_t)(4*k4+2)*HID+c0);
            float2 w3=*(const float2*)(wtfc1+(size_t)(4*k4+3)*HID+c0);
            #pragma unroll
            for (int i=0;i<8;i++){
                float4 a=*(const float4*)(s_in+(rb+i)*INP+4*k4);
                ax0[i]+=a.x*w0.x+a.y*w1.x+a.z*w2.x+a.w*w3.x;
                ax1[i]+=a.x*w0.y+a.y*w1.y+a.z*w2.y+a.w*w3.y;
            }
        }
        float fb0=cb[OB_FC1B+c0], fb1=cb[OB_FC1B+c0+1];
        #pragma unroll
        for (int i=0;i<8;i++){
            float v0=ax0[i]+fb0, v1=ax1[i]+fb1;
            s_x[(rb+i)*HID+c0]  =v0>0.f?v0:0.f;
            s_x[(rb+i)*HID+c0+1]=v1>0.f?v1:0.f;
        }
    }
    __syncthreads();

    // ---- fused GRU: one sweep, 4 accumulator sets x 2 cols ----
    float h0[8], h1[8];
    {
        float sr0[8],sr1[8],sz0[8],sz1[8],sn0[8],sn1[8],sh0[8],sh1[8];
        #pragma unroll
        for (int i=0;i<8;i++){ sr0[i]=sr1[i]=sz0[i]=sz1[i]=sn0[i]=sn1[i]=sh0[i]=sh1[i]=0.f; }
        for (int k4=0;k4<HID/4;k4++){
            float av[8][4];
            #pragma unroll
            for (int i=0;i<8;i++){
                float4 tmp=*(const float4*)(s_x+(rb+i)*HID+4*k4);
                av[i][0]=tmp.x; av[i][1]=tmp.y; av[i][2]=tmp.z; av[i][3]=tmp.w;
            }
            const float* wi = wtih + (size_t)(4*k4)*G3 + c0;
            #pragma unroll
            for (int kk=0;kk<4;kk++){
                float2 wr=*(const float2*)(wi+kk*G3);
                float2 wz=*(const float2*)(wi+kk*G3+256);
                float2 wn=*(const float2*)(wi+kk*G3+512);
                #pragma unroll
                for (int i=0;i<8;i++){
                    float a=av[i][kk];
                    sr0[i]+=a*wr.x; sr1[i]+=a*wr.y;
                    sz0[i]+=a*wz.x; sz1[i]+=a*wz.y;
                    sn0[i]+=a*wn.x; sn1[i]+=a*wn.y;
                }
            }
            #pragma unroll
            for (int i=0;i<8;i++){
                float4 tmp=*(const float4*)(s_oh+(rb+i)*HID+4*k4);
                av[i][0]=tmp.x; av[i][1]=tmp.y; av[i][2]=tmp.z; av[i][3]=tmp.w;
            }
            const float* wh = wthh + (size_t)(4*k4)*G3 + c0;
            #pragma unroll
            for (int kk=0;kk<4;kk++){
                float2 wr=*(const float2*)(wh+kk*G3);
                float2 wz=*(const float2*)(wh+kk*G3+256);
                float2 wn=*(const float2*)(wh+kk*G3+512);
                #pragma unroll
                for (int i=0;i<8;i++){
                    float b=av[i][kk];
                    sr0[i]+=b*wr.x; sr1[i]+=b*wr.y;
                    sz0[i]+=b*wz.x; sz1[i]+=b*wz.y;
                    sh0[i]+=b*wn.x; sh1[i]+=b*wn.y;
                }
            }
        }
        float bir0=cb[OB_BIH+c0],     bir1=cb[OB_BIH+c0+1];
        float bhr0=cb[OB_BHH+c0],     bhr1=cb[OB_BHH+c0+1];
        float biz0=cb[OB_BIH+256+c0], biz1=cb[OB_BIH+256+c0+1];
        float bhz0=cb[OB_BHH+256+c0], bhz1=cb[OB_BHH+256+c0+1];
        float bin0=cb[OB_BIH+512+c0], bin1=cb[OB_BIH+512+c0+1];
        float bhn0=cb[OB_BHH+512+c0], bhn1=cb[OB_BHH+512+c0+1];
        #pragma unroll
        for (int i=0;i<8;i++){
            float r0=sig_(sr0[i]+bir0+bhr0);
            float r1=sig_(sr1[i]+bir1+bhr1);
            float n0=tanhf(sn0[i]+bin0 + r0*(sh0[i]+bhn0));
            float n1=tanhf(sn1[i]+bin1 + r1*(sh1[i]+bhn1));
            float z0=sig_(sz0[i]+biz0+bhz0);
            float z1=sig_(sz1[i]+biz1+bhz1);
            h0[i]=(1.f-z0)*n0 + z0*s_oh[(rb+i)*HID+c0];
            h1[i]=(1.f-z1)*n1 + z1*s_oh[(rb+i)*HID+c0+1];
        }
    }
    #pragma unroll
    for (int i=0;i<8;i++){
        size_t ro=(size_t)(row0+rb+i)*HID + c0;
        stout2(dout, HOFF+ro, h0[i], h1[i], f32);
    }
    __syncthreads();   // all reads of s_in/s_x/s_oh done

    // phase 2: hc <- h
    #pragma unroll
    for (int i=0;i<8;i++){
        s_hc[(rb+i)*CAT+c0]  =h0[i];
        s_hc[(rb+i)*CAT+c0+1]=h1[i];
    }
    __syncthreads();

    // ---- rollout: 5 x (dec -> argmax -> trans) ----
    const int rr=t>>4, aa=t&15;     // dec mapping
    const int rg4=t>>6;             // trans: 4-row group
    const int c4=(t&63)*4;          // trans: 4 cols
    const int bb=(t>>7)*8;          // batch row base for ac
    for (int s=0;s<5;s++){
        // dec: q_inf
        float acc=cb[OB_DECB+aa];
        for (int k4=0;k4<HID/4;k4++){
            float4 hv=*(const float4*)(s_hc+rr*CAT+4*k4);
            float4 dv=*(const float4*)(decw+aa*HID+4*k4);
            acc += hv.x*dv.x + hv.y*dv.y + hv.z*dv.z + hv.w*dv.w;
        }
        trajb[(size_t)(row0+rr)*TRAJD + s*NACT + aa] = f2bf(acc);
        if (s==0){
            // qbase = q_local + 0.5*(qij_b + h @ qij[:, :256]^T)
            float q2=cb[OB_QIJB+aa];
            for (int k4=0;k4<HID/4;k4++){
                float4 hv=*(const float4*)(s_hc+rr*CAT+4*k4);
                float4 qv=*(const float4*)(qijw+aa*QIJK+4*k4);
                q2 += hv.x*qv.x + hv.y*qv.y + hv.z*qv.z + hv.w*qv.w;
            }
            qbase[(size_t)(row0+rr)*NACT+aa] = acc + 0.5f*q2;
        }
        if (s==4) break;
        s_q[rr*16+aa]=acc;
        __syncthreads();
        // argmax (t<16) in parallel with trans-main k-loop
        if (t<16){
            float m=s_q[t*16]; int mi=0;
            #pragma unroll
            for (int a=1;a<NACT;a++){ float v=s_q[t*16+a]; if (v>m){m=v;mi=a;} }
            s_ac[t]=(float)mi;
        }
        float tc0[4],tc1[4],tc2[4],tc3[4];
        #pragma unroll
        for (int j=0;j<4;j++){ float tb=cb[OB_TRB+c4+j]; tc0[j]=tb; tc1[j]=tb; tc2[j]=tb; tc3[j]=tb; }
        for (int k4=0;k4<HID/4;k4++){
            float4 w0=*(const float4*)(wttr+(size_t)(4*k4+0)*HID+c4);
            float4 w1=*(const float4*)(wttr+(size_t)(4*k4+1)*HID+c4);
            float4 w2=*(const float4*)(wttr+(size_t)(4*k4+2)*HID+c4);
            float4 w3=*(const float4*)(wttr+(size_t)(4*k4+3)*HID+c4);
            float4 a;
            a=*(const float4*)(s_hc+(rg4*4+0)*CAT+4*k4);
            tc0[0]+=a.x*w0.x+a.y*w1.x+a.z*w2.x+a.w*w3.x;
            tc0[1]+=a.x*w0.y+a.y*w1.y+a.z*w2.y+a.w*w3.y;
            tc0[2]+=a.x*w0.z+a.y*w1.z+a.z*w2.z+a.w*w3.z;
            tc0[3]+=a.x*w0.w+a.y*w1.w+a.z*w2.w+a.w*w3.w;
            a=*(const float4*)(s_hc+(rg4*4+1)*CAT+4*k4);
            tc1[0]+=a.x*w0.x+a.y*w1.x+a.z*w2.x+a.w*w3.x;
            tc1[1]+=a.x*w0.y+a.y*w1.y+a.z*w2.y+a.w*w3.y;
            tc1[2]+=a.x*w0.z+a.y*w1.z+a.z*w2.z+a.w*w3.z;
            tc1[3]+=a.x*w0.w+a.y*w1.w+a.z*w2.w+a.w*w3.w;
            a=*(const float4*)(s_hc+(rg4*4+2)*CAT+4*k4);
            tc2[0]+=a.x*w0.x+a.y*w1.x+a.z*w2.x+a.w*w3.x;
            tc2[1]+=a.x*w0.y+a.y*w1.y+a.z*w2.y+a.w*w3.y;
            tc2[2]+=a.x*w0.z+a.y*w1.z+a.z*w2.z+a.w*w3.z;
            tc2[3]+=a.x*w0.w+a.y*w1.w+a.z*w2.w+a.w*w3.w;
            a=*(const float4*)(s_hc+(rg4*4+3)*CAT+4*k4);
            tc3[0]+=a.x*w0.x+a.y*w1.x+a.z*w2.x+a.w*w3.x;
            tc3[1]+=a.x*w0.y+a.y*w1.y+a.z*w2.y+a.w*w3.y;
            tc3[2]+=a.x*w0.z+a.y*w1.z+a.z*w2.z+a.w*w3.z;
            tc3[3]+=a.x*w0.w+a.y*w1.w+a.z*w2.w+a.w*w3.w;
        }
        __syncthreads();   // s_q/s_hc reads done, s_ac ready
        {
            float ac[4]={0.f,0.f,0.f,0.f};
            #pragma unroll
            for (int jj=0;jj<8;jj++){
                float am=s_ac[bb+jj];
                float4 w=*(const float4*)(wttr+(size_t)(256+jj)*HID+c4);
                ac[0]+=am*w.x; ac[1]+=am*w.y; ac[2]+=am*w.z; ac[3]+=am*w.w;
            }
            *(float4*)(s_hc+(rg4*4+0)*CAT+c4)=make_float4(tc0[0]+ac[0],tc0[1]+ac[1],tc0[2]+ac[2],tc0[3]+ac[3]);
            *(float4*)(s_hc+(rg4*4+1)*CAT+c4)=make_float4(tc1[0]+ac[0],tc1[1]+ac[1],tc1[2]+ac[2],tc1[3]+ac[3]);
            *(float4*)(s_hc+(rg4*4+2)*CAT+c4)=make_float4(tc2[0]+ac[0],tc2[1]+ac[1],tc2[2]+ac[2],tc2[3]+ac[3]);
            *(float4*)(s_hc+(rg4*4+3)*CAT+c4)=make_float4(tc3[0]+ac[0],tc3[1]+ac[1],tc3[2]+ac[2],tc3[3]+ac[3]);
        }
        __syncthreads();
    }
}

// ---------------- k4: attention + message head, 4 batches per block ----------------
__global__ __launch_bounds__(256) void k4_attn(
    const float* __restrict__ ws, void* __restrict__ dout, const int* __restrict__ flagp)
{
    __shared__ float s_w3[3][QD][84];
    __shared__ float s_qm[NACT][68];
    __shared__ float s_traj[NAG][TRAJD];
    __shared__ float s_qkv[3][NAG][68];
    __shared__ float s_att[NAG][NAG];
    __shared__ float s_msg[NAG][68];

    const int f32 = *flagp;
    const int t = threadIdx.x;
    const float* cb = ws + WS_CB;
    const u16* trajb = (const u16*)(ws + WS_TRAJ);
    const float* qbase = ws + WS_QBASE;

    for (int i=t;i<3*QD*TRAJD;i+=256){ int w=i/5120, rem=i%5120, d=rem/80, j=rem%80; s_w3[w][d][j]=ws[WS_QW+i]; }
    for (int i=t;i<NACT*MESS;i+=256){ int a=i>>6, m=i&63; s_qm[a][m]=ws[WS_QIJW + a*QIJK + HID + m]; }

    for (int b=0;b<4;b++){
        const int row0 = (blockIdx.x*4 + b)*NAG;
        __syncthreads();   // staging done / prev-iter reads done
        for (int i=t;i<NAG*TRAJD;i+=256) s_traj[i/80][i%80]=bf2f(trajb[(size_t)row0*TRAJD+i]);
        __syncthreads();

        for (int o=t;o<3*NAG*QD;o+=256){      // q/k/v projections (K=80)
            int which=o>>9, n=(o>>6)&7, d=o&63;
            float acc=cb[OB_QB + which*64 + d];
            for (int j4=0;j4<TRAJD/4;j4++){
                float4 tv=*(const float4*)(&s_traj[n][4*j4]);
                float4 wv=*(const float4*)(&s_w3[which][d][4*j4]);
                acc += tv.x*wv.x + tv.y*wv.y + tv.z*wv.z + tv.w*wv.w;
            }
            s_qkv[which][n][d]=acc;
        }
        __syncthreads();
        if (t<NAG*NAG){                        // scores / sqrt(MESS)
            int n=t>>3,m=t&7;
            float acc=0.f;
            for (int d4=0;d4<MESS/4;d4++){
                float4 qv=*(const float4*)(&s_qkv[0][n][4*d4]);
                float4 kv=*(const float4*)(&s_qkv[1][m][4*d4]);
                acc += qv.x*kv.x + qv.y*kv.y + qv.z*kv.z + qv.w*kv.w;
            }
            s_att[n][m]=acc*0.125f;
        }
        __syncthreads();
        if (t<NAG){                            // softmax over m
            float m=s_att[t][0];
            #pragma unroll
            for (int j=1;j<NAG;j++) m=fmaxf(m,s_att[t][j]);
            float e[NAG]; float sum=0.f;
            #pragma unroll
            for (int j=0;j<NAG;j++){ e[j]=expf(s_att[t][j]-m); sum+=e[j]; }
            float inv=1.f/sum;
            #pragma unroll
            for (int j=0;j<NAG;j++) s_att[t][j]=e[j]*inv;
        }
        __syncthreads();
        for (int o=t;o<NAG*MESS;o+=256){       // message (512 work items: MUST grid-stride, was the round-4 bug)
            int n=o>>6,d=o&63;
            float acc=0.f;
            #pragma unroll
            for (int m=0;m<NAG;m++) acc += s_att[n][m]*s_qkv[2][m][d];
            s_msg[n][d]=acc;
        }
        __syncthreads();
        if (t<NAG*NACT){                       // q = qbase + 0.5 * msg @ qij_m^T
            int r=t>>4,a=t&15;
            float qi=0.f;
            for (int m4=0;m4<MESS/4;m4++){
                float4 mv=*(const float4*)(&s_msg[r][4*m4]);
                float4 qv=*(const float4*)(&s_qm[a][4*m4]);
                qi += mv.x*qv.x + mv.y*qv.y + mv.z*qv.z + mv.w*qv.w;
            }
            float q = qbase[(size_t)(row0+r)*NACT+a] + 0.5f*qi;
            stout1(dout, (size_t)(row0+r)*NACT+a, q, f32);
        }
    }
}

extern "C" void kernel_launch(void* const* d_in, const int* in_sizes, int n_in,
                              void* d_out, int out_size, void* d_ws, size_t ws_size,
                              hipStream_t stream)
{
    (void)in_sizes; (void)n_in; (void)out_size; (void)ws_size;
    const void* inputs = d_in[0];
    const void* oldh   = d_in[1];
    float* ws = (float*)d_ws;
    int* flagp = (int*)(ws + WS_FLAG);

    k_det<<<1,64,0,stream>>>(inputs, flagp);
    k0_prep<<<768,256,0,stream>>>(d_in[2],d_in[4],d_in[5],d_in[10],
                                  d_in[8],d_in[12],d_in[14],d_in[16],d_in[18],
                                  d_in[3],d_in[6],d_in[7],d_in[9],
                                  d_in[11],d_in[13],d_in[15],d_in[17],d_in[19],
                                  ws, flagp);
    k12_gru_rollout<<<2048,256,0,stream>>>(inputs, oldh, ws, d_out, flagp);
    k4_attn<<<1024,256,0,stream>>>(ws, d_out, flagp);
}